// Round 1
// baseline (630.466 us; speedup 1.0000x reference)
//
#include <hip/hip_runtime.h>
#include <hip/hip_bf16.h>

typedef unsigned short u16;
typedef unsigned int   u32;
typedef __attribute__((ext_vector_type(8))) short short8;   // 8 bf16 = 4 VGPR (MFMA A/B frag)
typedef __attribute__((ext_vector_type(4))) float f32x4;    // MFMA C/D frag

#define T_TOK 4096
#define HDIM  2048
#define NEXP  16
#define IDIM  1024
#define SIDIM 4096
#define RCAP  6144   /* T + E*128 worst-case padded gathered rows */
#define NTIL  48     /* RCAP/128 row tiles */

// ---- workspace layout (bytes); total ~88.2 MB ----
#define O_WT      0u                         // float[T]
#define O_EIDX    16384u                     // int[T]
#define O_CNT     32768u                     // int[16]
#define O_POS     32832u                     // int[16]
#define O_PADOFF  32896u                     // int[17]
#define O_TILEEXP 33024u                     // int[64]
#define O_TOKROW  33280u                     // int[RCAP]
#define O_XBF     65536u                     // bf16[T*H]
#define O_XSC     (O_XBF + 2u*T_TOK*HDIM)    // bf16[RCAP*H]
#define O_ACTS    (O_XSC + 2u*RCAP*HDIM)     // bf16[T*SI]
#define O_ACTR    (O_ACTS + 2u*T_TOK*SIDIM)  // bf16[RCAP*I]

__device__ __forceinline__ u16 f2b(float f) {  // fp32 -> bf16 bits, RNE
  u32 u = __float_as_uint(f);
  u = (u + 0x7FFFu + ((u >> 16) & 1u)) >> 16;
  return (u16)u;
}

// ---------------- router: fp64-accurate logits, top-1, sigmoid ----------------
__global__ __launch_bounds__(256) void router_k(
    const float* __restrict__ x, const float* __restrict__ rw,
    float* __restrict__ wt, int* __restrict__ eidx, int* __restrict__ cnt) {
  int w = threadIdx.x >> 6, l = threadIdx.x & 63;
  int t = blockIdx.x * 4 + w;
  double acc[NEXP];
#pragma unroll
  for (int e = 0; e < NEXP; ++e) acc[e] = 0.0;
  const float* xp = x + (size_t)t * HDIM;
  for (int hb = 0; hb < HDIM; hb += 256) {
    float4 xv = *(const float4*)(xp + hb + l * 4);
#pragma unroll
    for (int e = 0; e < NEXP; ++e) {
      float4 wv = *(const float4*)(rw + (size_t)e * HDIM + hb + l * 4);
      acc[e] += (double)xv.x * wv.x + (double)xv.y * wv.y
              + (double)xv.z * wv.z + (double)xv.w * wv.w;
    }
  }
#pragma unroll
  for (int e = 0; e < NEXP; ++e) {
    double v = acc[e];
#pragma unroll
    for (int off = 32; off; off >>= 1) v += __shfl_xor(v, off, 64);
    acc[e] = v;
  }
  if (l == 0) {
    double best = acc[0]; int be = 0;
#pragma unroll
    for (int e = 1; e < NEXP; ++e) if (acc[e] > best) { best = acc[e]; be = e; }
    wt[t] = 1.0f / (1.0f + __expf(-(float)best));
    eidx[t] = be;
    atomicAdd(&cnt[be], 1);
  }
}

// ---------------- bucket scan: padded segment offsets + tile->expert map ----------------
__global__ void scan_k(const int* __restrict__ cnt, int* __restrict__ pad_off,
                       int* __restrict__ tile_exp, int* __restrict__ pos,
                       int* __restrict__ tok_row) {
  if (threadIdx.x == 0) {
    for (int i = 0; i < 64; ++i) tile_exp[i] = -1;
    int run = 0;
    for (int e = 0; e < NEXP; ++e) {
      pad_off[e] = run;
      int pc = ((cnt[e] + 127) >> 7) << 7;
      for (int tt = run >> 7; tt < (run + pc) >> 7; ++tt) tile_exp[tt] = e;
      run += pc;
      pos[e] = 0;
    }
    pad_off[NEXP] = run;
  }
  for (int i = threadIdx.x; i < RCAP; i += 256) tok_row[i] = -1;
}

__global__ void assign_k(const int* __restrict__ eidx, const int* __restrict__ pad_off,
                         int* __restrict__ pos, int* __restrict__ tok_row) {
  int t = blockIdx.x * 256 + threadIdx.x;
  if (t >= T_TOK) return;
  int e = eidx[t];
  int r = atomicAdd(&pos[e], 1);
  tok_row[pad_off[e] + r] = t;
}

// ---------------- convert x -> bf16, and gathered+weighted x_scaled ----------------
__global__ __launch_bounds__(256) void cvt_k(
    const float* __restrict__ x, const float* __restrict__ wt,
    const int* __restrict__ tok_row, u16* __restrict__ xbf, u16* __restrict__ xsc) {
  int row = blockIdx.x;
  int tid = threadIdx.x;
  if (row < T_TOK) {
    const float* src = x + (size_t)row * HDIM;
    u16* dst = xbf + (size_t)row * HDIM;
#pragma unroll
    for (int i = 0; i < 2; ++i) {
      int c = i * 1024 + tid * 4;
      float4 v = *(const float4*)(src + c);
      uint2 o;
      o.x = (u32)f2b(v.x) | ((u32)f2b(v.y) << 16);
      o.y = (u32)f2b(v.z) | ((u32)f2b(v.w) << 16);
      *(uint2*)(dst + c) = o;
    }
  } else {
    int g = row - T_TOK;
    u16* dst = xsc + (size_t)g * HDIM;
    int t = tok_row[g];
    if (t < 0) {
      uint2 z; z.x = 0u; z.y = 0u;
#pragma unroll
      for (int i = 0; i < 2; ++i) *(uint2*)(dst + i * 1024 + tid * 4) = z;
    } else {
      float s = wt[t];
      const float* src = x + (size_t)t * HDIM;
#pragma unroll
      for (int i = 0; i < 2; ++i) {
        int c = i * 1024 + tid * 4;
        float4 v = *(const float4*)(src + c);
        uint2 o;
        o.x = (u32)f2b(v.x * s) | ((u32)f2b(v.y * s) << 16);
        o.y = (u32)f2b(v.z * s) | ((u32)f2b(v.w * s) << 16);
        *(uint2*)(dst + c) = o;
      }
    }
  }
}

// ================= GEMM kernels: 128x64 tile, BK=64, 4 waves (2x2), 16x16x32 bf16 =================
// A: bf16 [M,K] row-major global. B: fp32 [K,N] row-major global, converted+transposed
// into LDS [n][72] during staging. A LDS is XOR-swizzled per row to kill b128 read conflicts.

template<bool ROUTED>
__global__ __launch_bounds__(256) void gemm_gu(
    const u16* __restrict__ A, int lda,
    const float* __restrict__ Bg0, const float* __restrict__ Bu0, int ldb,
    int K, u16* __restrict__ act, int ldact,
    const int* __restrict__ tile_exp) {
  __shared__ __align__(16) u16 As[128 * 64];
  __shared__ __align__(16) u16 Bgs[64 * 72];
  __shared__ __align__(16) u16 Bus[64 * 72];
  const int tid = threadIdx.x;
  const int w = tid >> 6, l = tid & 63;
  const int wm = w >> 1, wn = w & 1;
  const int m0 = blockIdx.y * 128, n0 = blockIdx.x * 64;
  const float* Bg = Bg0;
  const float* Bu = Bu0;
  if (ROUTED) {
    int e = tile_exp[blockIdx.y];
    if (e < 0) return;
    size_t off = (size_t)e * (size_t)K * (size_t)ldb;
    Bg += off; Bu += off;
  }
  f32x4 accg[4][2], accu[4][2];
#pragma unroll
  for (int i = 0; i < 4; ++i)
#pragma unroll
    for (int j = 0; j < 2; ++j)
#pragma unroll
      for (int r = 0; r < 4; ++r) { accg[i][j][r] = 0.0f; accu[i][j][r] = 0.0f; }

  const int ra = tid >> 3;        // 0..31
  const int ca = (tid & 7) * 8;   // 0..56
  const u16* Ab = A + (size_t)m0 * lda;

  for (int k0 = 0; k0 < K; k0 += 64) {
    __syncthreads();
    // stage A (bf16 -> LDS, row-XOR swizzle)
#pragma unroll
    for (int i = 0; i < 4; ++i) {
      int r = ra + 32 * i;
      int4 v = *(const int4*)(Ab + (size_t)r * lda + k0 + ca);
      *(int4*)&As[r * 64 + (ca ^ ((r & 7) * 8))] = v;
    }
    // stage Bg, Bu: fp32 [K,N] -> bf16 transposed LDS [n][72]
    {
      const float* bp = Bg + (size_t)(k0 + w * 16) * ldb + n0 + l;
      u16 h[16];
#pragma unroll
      for (int i = 0; i < 16; ++i) h[i] = f2b(bp[(size_t)i * ldb]);
#pragma unroll
      for (int j = 0; j < 4; ++j) {
        uint2 v; v.x = (u32)h[4*j] | ((u32)h[4*j+1] << 16);
        v.y = (u32)h[4*j+2] | ((u32)h[4*j+3] << 16);
        *(uint2*)&Bgs[l * 72 + w * 16 + j * 4] = v;
      }
      bp = Bu + (size_t)(k0 + w * 16) * ldb + n0 + l;
#pragma unroll
      for (int i = 0; i < 16; ++i) h[i] = f2b(bp[(size_t)i * ldb]);
#pragma unroll
      for (int j = 0; j < 4; ++j) {
        uint2 v; v.x = (u32)h[4*j] | ((u32)h[4*j+1] << 16);
        v.y = (u32)h[4*j+2] | ((u32)h[4*j+3] << 16);
        *(uint2*)&Bus[l * 72 + w * 16 + j * 4] = v;
      }
    }
    __syncthreads();
#pragma unroll
    for (int kh = 0; kh < 2; ++kh) {
      short8 af[4];
#pragma unroll
      for (int mf = 0; mf < 4; ++mf) {
        int r = wm * 64 + mf * 16 + (l & 15);
        int c = (kh * 32 + (l >> 4) * 8) ^ ((r & 7) * 8);
        af[mf] = *(const short8*)&As[r * 64 + c];
      }
      short8 bgf[2], buf2[2];
#pragma unroll
      for (int nf = 0; nf < 2; ++nf) {
        int n = wn * 32 + nf * 16 + (l & 15);
        int c = kh * 32 + (l >> 4) * 8;
        bgf[nf]  = *(const short8*)&Bgs[n * 72 + c];
        buf2[nf] = *(const short8*)&Bus[n * 72 + c];
      }
#pragma unroll
      for (int mf = 0; mf < 4; ++mf)
#pragma unroll
        for (int nf = 0; nf < 2; ++nf) {
          accg[mf][nf] = __builtin_amdgcn_mfma_f32_16x16x32_bf16(af[mf], bgf[nf],  accg[mf][nf], 0, 0, 0);
          accu[mf][nf] = __builtin_amdgcn_mfma_f32_16x16x32_bf16(af[mf], buf2[nf], accu[mf][nf], 0, 0, 0);
        }
    }
  }
  // epilogue: act = silu(g) * u -> bf16
#pragma unroll
  for (int mf = 0; mf < 4; ++mf)
#pragma unroll
    for (int nf = 0; nf < 2; ++nf) {
      int col = n0 + wn * 32 + nf * 16 + (l & 15);
#pragma unroll
      for (int r = 0; r < 4; ++r) {
        int row = m0 + wm * 64 + mf * 16 + (l >> 4) * 4 + r;
        float g = accg[mf][nf][r], u = accu[mf][nf][r];
        float s = g / (1.0f + __expf(-g));
        act[(size_t)row * ldact + col] = f2b(s * u);
      }
    }
}

template<bool ROUTED>
__global__ __launch_bounds__(256) void gemm_down(
    const u16* __restrict__ A, int lda,
    const float* __restrict__ B0, int ldb, int K,
    float* __restrict__ out, int ldout,
    const int* __restrict__ tile_exp, const int* __restrict__ tok_row) {
  __shared__ __align__(16) u16 As[128 * 64];
  __shared__ __align__(16) u16 Bs[64 * 72];
  const int tid = threadIdx.x;
  const int w = tid >> 6, l = tid & 63;
  const int wm = w >> 1, wn = w & 1;
  const int m0 = blockIdx.y * 128, n0 = blockIdx.x * 64;
  const float* B = B0;
  if (ROUTED) {
    int e = tile_exp[blockIdx.y];
    if (e < 0) return;
    B += (size_t)e * (size_t)K * (size_t)ldb;
  }
  f32x4 acc[4][2];
#pragma unroll
  for (int i = 0; i < 4; ++i)
#pragma unroll
    for (int j = 0; j < 2; ++j)
#pragma unroll
      for (int r = 0; r < 4; ++r) acc[i][j][r] = 0.0f;

  const int ra = tid >> 3;
  const int ca = (tid & 7) * 8;
  const u16* Ab = A + (size_t)m0 * lda;

  for (int k0 = 0; k0 < K; k0 += 64) {
    __syncthreads();
#pragma unroll
    for (int i = 0; i < 4; ++i) {
      int r = ra + 32 * i;
      int4 v = *(const int4*)(Ab + (size_t)r * lda + k0 + ca);
      *(int4*)&As[r * 64 + (ca ^ ((r & 7) * 8))] = v;
    }
    {
      const float* bp = B + (size_t)(k0 + w * 16) * ldb + n0 + l;
      u16 h[16];
#pragma unroll
      for (int i = 0; i < 16; ++i) h[i] = f2b(bp[(size_t)i * ldb]);
#pragma unroll
      for (int j = 0; j < 4; ++j) {
        uint2 v; v.x = (u32)h[4*j] | ((u32)h[4*j+1] << 16);
        v.y = (u32)h[4*j+2] | ((u32)h[4*j+3] << 16);
        *(uint2*)&Bs[l * 72 + w * 16 + j * 4] = v;
      }
    }
    __syncthreads();
#pragma unroll
    for (int kh = 0; kh < 2; ++kh) {
      short8 af[4];
#pragma unroll
      for (int mf = 0; mf < 4; ++mf) {
        int r = wm * 64 + mf * 16 + (l & 15);
        int c = (kh * 32 + (l >> 4) * 8) ^ ((r & 7) * 8);
        af[mf] = *(const short8*)&As[r * 64 + c];
      }
      short8 bf[2];
#pragma unroll
      for (int nf = 0; nf < 2; ++nf) {
        int n = wn * 32 + nf * 16 + (l & 15);
        int c = kh * 32 + (l >> 4) * 8;
        bf[nf] = *(const short8*)&Bs[n * 72 + c];
      }
#pragma unroll
      for (int mf = 0; mf < 4; ++mf)
#pragma unroll
        for (int nf = 0; nf < 2; ++nf)
          acc[mf][nf] = __builtin_amdgcn_mfma_f32_16x16x32_bf16(af[mf], bf[nf], acc[mf][nf], 0, 0, 0);
    }
  }
#pragma unroll
  for (int mf = 0; mf < 4; ++mf)
#pragma unroll
    for (int nf = 0; nf < 2; ++nf) {
      int col = n0 + wn * 32 + nf * 16 + (l & 15);
#pragma unroll
      for (int r = 0; r < 4; ++r) {
        int grow = m0 + wm * 64 + mf * 16 + (l >> 4) * 4 + r;
        float v = acc[mf][nf][r];
        if (ROUTED) {
          int t = tok_row[grow];
          if (t >= 0) out[(size_t)t * ldout + col] += v;
        } else {
          out[(size_t)grow * ldout + col] = v;
        }
      }
    }
}

extern "C" void kernel_launch(void* const* d_in, const int* in_sizes, int n_in,
                              void* d_out, int out_size, void* d_ws, size_t ws_size,
                              hipStream_t stream) {
  const float* x   = (const float*)d_in[0];
  const float* rw  = (const float*)d_in[1];
  const float* wg  = (const float*)d_in[2];
  const float* wu  = (const float*)d_in[3];
  const float* wd  = (const float*)d_in[4];
  const float* wsg = (const float*)d_in[5];
  const float* wsu = (const float*)d_in[6];
  const float* wsd = (const float*)d_in[7];
  float* out = (float*)d_out;
  char* ws = (char*)d_ws;

  float* wt     = (float*)(ws + O_WT);
  int* eidx     = (int*)(ws + O_EIDX);
  int* cnt      = (int*)(ws + O_CNT);
  int* pos      = (int*)(ws + O_POS);
  int* pad_off  = (int*)(ws + O_PADOFF);
  int* tile_exp = (int*)(ws + O_TILEEXP);
  int* tok_row  = (int*)(ws + O_TOKROW);
  u16* xbf      = (u16*)(ws + O_XBF);
  u16* xsc      = (u16*)(ws + O_XSC);
  u16* acts     = (u16*)(ws + O_ACTS);
  u16* actr     = (u16*)(ws + O_ACTR);

  hipMemsetAsync(ws + O_CNT, 0, 128, stream);  // cnt + pos
  router_k<<<T_TOK / 4, 256, 0, stream>>>(x, rw, wt, eidx, cnt);
  scan_k<<<1, 256, 0, stream>>>(cnt, pad_off, tile_exp, pos, tok_row);
  assign_k<<<T_TOK / 256, 256, 0, stream>>>(eidx, pad_off, pos, tok_row);
  cvt_k<<<T_TOK + RCAP, 256, 0, stream>>>(x, wt, tok_row, xbf, xsc);
  // shared expert gate/up: [4096,2048] x [2048,4096] -> act_sh bf16
  gemm_gu<false><<<dim3(SIDIM / 64, T_TOK / 128), 256, 0, stream>>>(
      xbf, HDIM, wsg, wsu, SIDIM, HDIM, acts, SIDIM, nullptr);
  // routed gate/up (grouped by expert tiles)
  gemm_gu<true><<<dim3(IDIM / 64, NTIL), 256, 0, stream>>>(
      xsc, HDIM, wg, wu, IDIM, HDIM, actr, IDIM, tile_exp);
  // shared down: writes d_out
  gemm_down<false><<<dim3(HDIM / 64, T_TOK / 128), 256, 0, stream>>>(
      acts, SIDIM, wsd, HDIM, SIDIM, out, HDIM, nullptr, nullptr);
  // routed down: scatter-add into d_out
  gemm_down<true><<<dim3(HDIM / 64, NTIL), 256, 0, stream>>>(
      actr, IDIM, wd, HDIM, IDIM, out, HDIM, tile_exp, tok_row);
}